// Round 6
// baseline (917.762 us; speedup 1.0000x reference)
//
#include <hip/hip_runtime.h>
#include <hip/hip_bf16.h>
#include <float.h>

#define BB 512
#define TT 40
#define CC 512
#define HH 512

typedef short bf16x8 __attribute__((ext_vector_type(8)));
typedef float f32x4 __attribute__((ext_vector_type(4)));
typedef unsigned short ushortx8 __attribute__((ext_vector_type(8)));

// LDS map (bytes): x-panel [48][1024B] | h-panel [48][1024B] | 8 acc slots 6144B | flags
#define LDSH 49152
#define LDSA 98304
#define LDSF 147456
#define LDSTOT 147968

__device__ __forceinline__ unsigned short f2bf(float f){
  union { float f; unsigned int i; } v; v.f = f;
  unsigned int r = v.i + 0x7fffu + ((v.i >> 16) & 1u);
  return (unsigned short)(r >> 16);
}

__device__ __forceinline__ bf16x8 load_sc0(const unsigned short* p){
  bf16x8 r;
  asm volatile("global_load_dwordx4 %0, %1, off sc0" : "=v"(r) : "v"(p));
  return r;
}
#define WAITV(N) do { asm volatile("s_waitcnt vmcnt(" #N ")" ::: "memory"); \
                      __builtin_amdgcn_sched_barrier(0); } while(0)

__device__ __forceinline__ float fast_sigmoid(float x){
  return __builtin_amdgcn_rcpf(1.f + __expf(-x));
}
__device__ __forceinline__ float fast_tanh(float x){
  return 1.f - 2.f*__builtin_amdgcn_rcpf(__expf(2.f*x) + 1.f);
}

// one wave per (b,t): convert 512 floats -> bf16, compute nonzero mask (transposed [T][B])
__global__ void prep_x_kernel(const float* __restrict__ x, unsigned short* __restrict__ xb,
                              float* __restrict__ maskT){
  int w = blockIdx.x*4 + (threadIdx.x>>6);
  int lane = threadIdx.x & 63;
  const float* src = x + (size_t)w*CC + lane*8;
  f32x4 a = *(const f32x4*)(src);
  f32x4 b = *(const f32x4*)(src+4);
  ushortx8 o;
  o[0]=f2bf(a[0]); o[1]=f2bf(a[1]); o[2]=f2bf(a[2]); o[3]=f2bf(a[3]);
  o[4]=f2bf(b[0]); o[5]=f2bf(b[1]); o[6]=f2bf(b[2]); o[7]=f2bf(b[3]);
  *(ushortx8*)(xb + (size_t)w*CC + lane*8) = o;
  bool nz = (a[0]!=0.f)||(a[1]!=0.f)||(a[2]!=0.f)||(a[3]!=0.f)||
            (b[0]!=0.f)||(b[1]!=0.f)||(b[2]!=0.f)||(b[3]!=0.f);
  unsigned long long bal = __ballot(nz);
  if (lane==0){
    int b_ = w / TT, t_ = w % TT;
    maskT[t_*BB + b_] = bal ? 1.0f : 0.0f;
  }
}

__global__ void cvt_kernel(const float* __restrict__ src, unsigned short* __restrict__ dst, int n){
  int i = blockIdx.x*blockDim.x + threadIdx.x;
  if (i < n) dst[i] = f2bf(src[i]);
}

__global__ void init_h_kernel(unsigned short* __restrict__ hb, unsigned int* __restrict__ ctr){
  int i = blockIdx.x*blockDim.x + threadIdx.x;
  hb[i] = 0;
  if (i < 8) ctr[i*32] = 0u;
}

// Persistent GRU: 256 WGs x 512 threads (8 waves), 1 WG/CU, 2 waves/SIMD.
// Waves 0-3 = x-waves (rows 32w..32w+31, K=512 x-panel): no serial dependency,
// run up to 2 steps ahead, write r/z/nx partials to double-buffered LDS slots.
// Waves 4-7 = h-waves (same rows, K=512 h-panel): group-barrier for h_t, compute
// r/z/nh partials, combine with partner's slot, gates, h store, barrier add.
// Wave i and i+4 share a SIMD -> x-wave hides h-wave's stalls.
__global__ __launch_bounds__(512, 2) void gru_persist_kernel(
    const unsigned short* __restrict__ xb,
    const unsigned short* __restrict__ wihF, const unsigned short* __restrict__ whhF,
    const unsigned short* __restrict__ wihB, const unsigned short* __restrict__ whhB,
    const float* __restrict__ bihF, const float* __restrict__ bhhF,
    const float* __restrict__ bihB, const float* __restrict__ bhhB,
    const float* __restrict__ maskT,
    unsigned short* __restrict__ hb,
    float* __restrict__ out, unsigned int* __restrict__ ctr)
{
  const int bid   = blockIdx.x;
  const int grp   = bid & 7;       // XCD-local group (round-robin dispatch)
  const int strip = bid >> 3;      // 0..31
  const int dir   = grp >> 2;
  const int bslab = grp & 3;
  const int b0 = bslab * 128;
  const int n0 = strip * 16;
  unsigned int* myctr = ctr + grp*32;

  const unsigned short* wih = dir ? wihB : wihF;
  const unsigned short* whh = dir ? whhB : whhF;
  const float* bih = dir ? bihB : bihF;
  const float* bhh = dir ? bhhB : bhhF;

  const int tid  = threadIdx.x;
  const int lane = tid & 63;
  const int lr   = lane & 15;
  const int lkg  = lane >> 4;
  const int wv   = tid >> 6;        // 0..7

  __shared__ __align__(16) char smem[LDSTOT];

  // ---- stage weights: x-panel rows 0-47 (gate g*16+col c), h-panel same; swizzled
  for (int q = tid; q < 6144; q += 512) {
    const int p_  = q >= 3072;
    const int r_  = p_ ? (q - 3072) : q;
    const int row = r_ >> 6;                  // 0..47
    const int kc  = (r_ & 63) * 8;            // 0..504
    const unsigned short* src =
        (p_ ? whh : wih) + ((size_t)((row>>4)*HH + n0 + (row&15)))*512 + kc;
    *(ushortx8*)(smem + p_*LDSH + row*1024 + ((kc*2) ^ ((row&15)<<4))) =
        *(const ushortx8*)src;
  }
  if (tid < 4)      *(unsigned int*)(smem + LDSF + tid*16) = 0u;          // produced
  else if (tid < 8) *(unsigned int*)(smem + LDSF + 256 + (tid-4)*16) = 0u; // consumed
  __syncthreads();   // the only workgroup barrier

  const int swz = lr << 4;

  if (wv < 4) {
    // ================= x-wave =================
    const int pair = wv;
    const int wrow = pair * 32;
    unsigned int* prod = (unsigned int*)(smem + LDSF + pair*16);
    unsigned int* cons = (unsigned int*)(smem + LDSF + 256 + pair*16);
    const char* wb_ = smem + lr*1024;   // x-panel, row lr of each gate block

    for (int t = 0; t < TT; ++t) {
      const int tx = dir ? (TT-1-t) : t;
      f32x4 ar[2], az[2], anx[2];
      #pragma unroll
      for (int mf=0; mf<2; ++mf){ ar[mf]=0.f; az[mf]=0.f; anx[mf]=0.f; }

      const unsigned short* xr0 = xb + ((size_t)(b0 + wrow + lr     )*TT + tx)*CC;
      const unsigned short* xr1 = xb + ((size_t)(b0 + wrow + 16 + lr)*TT + tx)*CC;

      #pragma unroll
      for (int kk = 0; kk < 16; ++kk) {
        const int ko = kk*32 + lkg*8;
        bf16x8 a0 = *(const bf16x8*)(xr0 + ko);
        bf16x8 a1 = *(const bf16x8*)(xr1 + ko);
        const int kbx = (ko*2) ^ swz;
        bf16x8 brf = *(const bf16x8*)(wb_ +         kbx);
        bf16x8 bzf = *(const bf16x8*)(wb_ + 16384 + kbx);
        bf16x8 bnf = *(const bf16x8*)(wb_ + 32768 + kbx);
        ar[0]  = __builtin_amdgcn_mfma_f32_16x16x32_bf16(a0, brf, ar[0],0,0,0);
        ar[1]  = __builtin_amdgcn_mfma_f32_16x16x32_bf16(a1, brf, ar[1],0,0,0);
        az[0]  = __builtin_amdgcn_mfma_f32_16x16x32_bf16(a0, bzf, az[0],0,0,0);
        az[1]  = __builtin_amdgcn_mfma_f32_16x16x32_bf16(a1, bzf, az[1],0,0,0);
        anx[0] = __builtin_amdgcn_mfma_f32_16x16x32_bf16(a0, bnf, anx[0],0,0,0);
        anx[1] = __builtin_amdgcn_mfma_f32_16x16x32_bf16(a1, bnf, anx[1],0,0,0);
      }

      // backpressure: slot (t&1) last used at t-2; wait until partner consumed it
      if (t >= 2) {
        const unsigned int tgt = (unsigned)(t-1);
        unsigned int spin = 0;
        while (__hip_atomic_load(cons, __ATOMIC_ACQUIRE, __HIP_MEMORY_SCOPE_WORKGROUP) < tgt
               && ++spin < (1u<<24))
          __builtin_amdgcn_s_sleep(1);
      }

      char* slot = smem + LDSA + (pair*2 + (t&1))*6144 + lane*16;
      *(f32x4*)(slot + 0*1024) = ar[0];
      *(f32x4*)(slot + 1*1024) = ar[1];
      *(f32x4*)(slot + 2*1024) = az[0];
      *(f32x4*)(slot + 3*1024) = az[1];
      *(f32x4*)(slot + 4*1024) = anx[0];
      *(f32x4*)(slot + 5*1024) = anx[1];
      if (lane == 0)
        __hip_atomic_fetch_add(prod, 1u, __ATOMIC_RELEASE, __HIP_MEMORY_SCOPE_WORKGROUP);
    }
  } else {
    // ================= h-wave =================
    const int pair = wv - 4;
    const int wrow = pair * 32;
    unsigned int* prod = (unsigned int*)(smem + LDSF + pair*16);
    unsigned int* cons = (unsigned int*)(smem + LDSF + 256 + pair*16);
    const char* wb_ = smem + LDSH + lr*1024;   // h-panel

    const int jj = n0 + lr;
    const float br  = bih[jj]        + bhh[jj];
    const float bz  = bih[HH + jj]   + bhh[HH + jj];
    const float bnx = bih[2*HH + jj];
    const float bnh = bhh[2*HH + jj];

    float omax[2][4], hreg[2][4];
    #pragma unroll
    for (int mf=0; mf<2; ++mf)
      #pragma unroll
      for (int j=0; j<4; ++j){ omax[mf][j] = -FLT_MAX; hreg[mf][j] = 0.f; }

    for (int t = 0; t < TT; ++t) {
      const int tx = dir ? (TT-1-t) : t;
      const int bi = t & 1;
      const unsigned short* hbin = hb + (size_t)(dir*2 + bi)      * (BB*HH);
      unsigned short* hbout      = hb + (size_t)(dir*2 + (bi^1))  * (BB*HH);

      f32x4 ar[2], az[2], anh[2];
      #pragma unroll
      for (int mf=0; mf<2; ++mf){ ar[mf]=0.f; az[mf]=0.f; anh[mf]=0.f; }

      const float* mrow = maskT + tx*BB + b0 + wrow + lkg*4;
      const f32x4 mk0 = *(const f32x4*)(mrow);
      const f32x4 mk1 = *(const f32x4*)(mrow + 16);

      // wait for step t's h (published by all h-waves of the group at end of t-1)
      if (t > 0) {
        const unsigned int tgt = 128u*(unsigned)t;
        unsigned int spin = 0;
        while (__hip_atomic_load(myctr, __ATOMIC_RELAXED, __HIP_MEMORY_SCOPE_AGENT) < tgt
               && ++spin < (1u<<24))
          __builtin_amdgcn_s_sleep(1);
      }
      WAITV(0);   // drain mask loads; vmcnt exact below

      const unsigned short* hr0 = hbin + (size_t)(b0 + wrow + lr     )*HH;
      const unsigned short* hr1 = hbin + (size_t)(b0 + wrow + 16 + lr)*HH;
      bf16x8 c0 = load_sc0(hr0 + lkg*8);
      bf16x8 c1 = load_sc0(hr1 + lkg*8);
      #pragma unroll
      for (int kk = 0; kk < 16; ++kk) {
        const int ko = kk*32 + lkg*8;
        bf16x8 p0, p1;
        if (kk < 15) { p0 = load_sc0(hr0 + ko + 32); p1 = load_sc0(hr1 + ko + 32); }
        const int kbx = (ko*2) ^ swz;
        bf16x8 brf = *(const bf16x8*)(wb_ +         kbx);
        bf16x8 bzf = *(const bf16x8*)(wb_ + 16384 + kbx);
        bf16x8 bnf = *(const bf16x8*)(wb_ + 32768 + kbx);
        if (kk < 15) { WAITV(2); } else { WAITV(0); }
        ar[0]  = __builtin_amdgcn_mfma_f32_16x16x32_bf16(c0, brf, ar[0],0,0,0);
        ar[1]  = __builtin_amdgcn_mfma_f32_16x16x32_bf16(c1, brf, ar[1],0,0,0);
        az[0]  = __builtin_amdgcn_mfma_f32_16x16x32_bf16(c0, bzf, az[0],0,0,0);
        az[1]  = __builtin_amdgcn_mfma_f32_16x16x32_bf16(c1, bzf, az[1],0,0,0);
        anh[0] = __builtin_amdgcn_mfma_f32_16x16x32_bf16(c0, bnf, anh[0],0,0,0);
        anh[1] = __builtin_amdgcn_mfma_f32_16x16x32_bf16(c1, bnf, anh[1],0,0,0);
        if (kk < 15) { c0 = p0; c1 = p1; }
      }

      // partner's x-partials for step t
      {
        unsigned int spin = 0;
        const unsigned int tgt = (unsigned)(t+1);
        while (__hip_atomic_load(prod, __ATOMIC_ACQUIRE, __HIP_MEMORY_SCOPE_WORKGROUP) < tgt
               && ++spin < (1u<<24))
          __builtin_amdgcn_s_sleep(1);
      }
      const char* slot = smem + LDSA + (pair*2 + (t&1))*6144 + lane*16;
      f32x4 px0 = *(const f32x4*)(slot + 0*1024);
      f32x4 px1 = *(const f32x4*)(slot + 1*1024);
      f32x4 pz0 = *(const f32x4*)(slot + 2*1024);
      f32x4 pz1 = *(const f32x4*)(slot + 3*1024);
      f32x4 pn0 = *(const f32x4*)(slot + 4*1024);
      f32x4 pn1 = *(const f32x4*)(slot + 5*1024);
      asm volatile("s_waitcnt lgkmcnt(0)" ::: "memory");
      if (lane == 0)
        __hip_atomic_fetch_add(cons, 1u, __ATOMIC_RELEASE, __HIP_MEMORY_SCOPE_WORKGROUP);
      ar[0] += px0; ar[1] += px1;
      az[0] += pz0; az[1] += pz1;
      const f32x4 anx0 = pn0, anx1 = pn1;

      // gates, register h carry, register max-pool
      #pragma unroll
      for (int mf=0; mf<2; ++mf){
        const f32x4 mk = mf ? mk1 : mk0;
        const f32x4 anx_ = mf ? anx1 : anx0;
        #pragma unroll
        for (int j=0; j<4; ++j){
          const int b = b0 + wrow + mf*16 + lkg*4 + j;
          const float rg = fast_sigmoid(ar[mf][j] + br);
          const float zg = fast_sigmoid(az[mf][j] + bz);
          const float ng = fast_tanh(anx_[j] + bnx + rg*(anh[mf][j] + bnh));
          const float hn = (1.f - zg)*ng + zg*hreg[mf][j];
          hreg[mf][j] = hn;
          hbout[(size_t)b*HH + jj] = f2bf(hn);
          const float cand = (mk[j] != 0.f) ? hn : -FLT_MAX;
          omax[mf][j] = fmaxf(omax[mf][j], cand);
        }
      }

      if (t < TT-1) {
        WAITV(0);   // own h stores drained to L2
        if (lane == 0)
          __hip_atomic_fetch_add(myctr, 1u, __ATOMIC_RELAXED, __HIP_MEMORY_SCOPE_AGENT);
      }
    }

    #pragma unroll
    for (int mf=0; mf<2; ++mf)
      #pragma unroll
      for (int j=0; j<4; ++j){
        const int b = b0 + wrow + mf*16 + lkg*4 + j;
        out[(size_t)b*(2*HH) + dir*HH + (n0 + lr)] = omax[mf][j];
      }
  }
}

extern "C" void kernel_launch(void* const* d_in, const int* in_sizes, int n_in,
                              void* d_out, int out_size, void* d_ws, size_t ws_size,
                              hipStream_t stream) {
  const float* x    = (const float*)d_in[0];
  const float* WihF = (const float*)d_in[1];
  const float* WhhF = (const float*)d_in[2];
  const float* bihF = (const float*)d_in[3];
  const float* bhhF = (const float*)d_in[4];
  const float* WihB = (const float*)d_in[5];
  const float* WhhB = (const float*)d_in[6];
  const float* bihB = (const float*)d_in[7];
  const float* bhhB = (const float*)d_in[8];
  float* out = (float*)d_out;

  char* ws = (char*)d_ws;
  unsigned short* xb    = (unsigned short*)(ws);              // B*T*C bf16
  unsigned short* wb    = (unsigned short*)(ws + 20971520);
  unsigned short* wihFb = wb;
  unsigned short* whhFb = wb + 786432;
  unsigned short* wihBb = wb + 2*786432;
  unsigned short* whhBb = wb + 3*786432;
  float* maskT = (float*)(ws + 27262976);                     // [T][B]
  unsigned short* hb = (unsigned short*)(ws + 27344896);      // [2dir][2buf][B][H] bf16
  unsigned int* ctr  = (unsigned int*)(ws + 29442048);        // 8 counters, 128B stride

  prep_x_kernel<<<BB*TT/4, 256, 0, stream>>>(x, xb, maskT);
  cvt_kernel<<<3072, 256, 0, stream>>>(WihF, wihFb, 786432);
  cvt_kernel<<<3072, 256, 0, stream>>>(WhhF, whhFb, 786432);
  cvt_kernel<<<3072, 256, 0, stream>>>(WihB, wihBb, 786432);
  cvt_kernel<<<3072, 256, 0, stream>>>(WhhB, whhBb, 786432);
  init_h_kernel<<<4096, 256, 0, stream>>>(hb, ctr);

  gru_persist_kernel<<<256, 512, 0, stream>>>(xb, wihFb, whhFb, wihBb, whhBb,
                                              bihF, bhhF, bihB, bhhB,
                                              maskT, hb, out, ctr);
}

// Round 7
// 370.927 us; speedup vs baseline: 2.4742x; 2.4742x over previous
//
#include <hip/hip_runtime.h>
#include <hip/hip_bf16.h>
#include <float.h>

#define BB 512
#define TT 40
#define CC 512
#define HH 512

typedef short bf16x8 __attribute__((ext_vector_type(8)));
typedef float f32x4 __attribute__((ext_vector_type(4)));
typedef unsigned short ushortx8 __attribute__((ext_vector_type(8)));

// LDS map (bytes): x-panel [48][1024B] | h-panel [48][1024B] | flags (arrive, go)
#define LDSH 49152
#define LDSF 98304
#define LDSTOT 98320

__device__ __forceinline__ unsigned short f2bf(float f){
  union { float f; unsigned int i; } v; v.f = f;
  unsigned int r = v.i + 0x7fffu + ((v.i >> 16) & 1u);
  return (unsigned short)(r >> 16);
}

__device__ __forceinline__ bf16x8 load_sc0(const unsigned short* p){
  bf16x8 r;
  asm volatile("global_load_dwordx4 %0, %1, off sc0" : "=v"(r) : "v"(p));
  return r;
}
#define WAITV(N) do { asm volatile("s_waitcnt vmcnt(" #N ")" ::: "memory"); \
                      __builtin_amdgcn_sched_barrier(0); } while(0)

__device__ __forceinline__ float fast_sigmoid(float x){
  return __builtin_amdgcn_rcpf(1.f + __expf(-x));
}
__device__ __forceinline__ float fast_tanh(float x){
  return 1.f - 2.f*__builtin_amdgcn_rcpf(__expf(2.f*x) + 1.f);
}

// one wave per (b,t): convert 512 floats -> bf16, compute nonzero mask (transposed [T][B])
__global__ void prep_x_kernel(const float* __restrict__ x, unsigned short* __restrict__ xb,
                              float* __restrict__ maskT){
  int w = blockIdx.x*4 + (threadIdx.x>>6);
  int lane = threadIdx.x & 63;
  const float* src = x + (size_t)w*CC + lane*8;
  f32x4 a = *(const f32x4*)(src);
  f32x4 b = *(const f32x4*)(src+4);
  ushortx8 o;
  o[0]=f2bf(a[0]); o[1]=f2bf(a[1]); o[2]=f2bf(a[2]); o[3]=f2bf(a[3]);
  o[4]=f2bf(b[0]); o[5]=f2bf(b[1]); o[6]=f2bf(b[2]); o[7]=f2bf(b[3]);
  *(ushortx8*)(xb + (size_t)w*CC + lane*8) = o;
  bool nz = (a[0]!=0.f)||(a[1]!=0.f)||(a[2]!=0.f)||(a[3]!=0.f)||
            (b[0]!=0.f)||(b[1]!=0.f)||(b[2]!=0.f)||(b[3]!=0.f);
  unsigned long long bal = __ballot(nz);
  if (lane==0){
    int b_ = w / TT, t_ = w % TT;
    maskT[t_*BB + b_] = bal ? 1.0f : 0.0f;
  }
}

// vectorized f32 -> bf16 weight convert (8 elems/thread)
__global__ void cvt_kernel(const float* __restrict__ src, unsigned short* __restrict__ dst, int n8){
  int i = blockIdx.x*blockDim.x + threadIdx.x;
  if (i < n8){
    f32x4 a = *(const f32x4*)(src + i*8);
    f32x4 b = *(const f32x4*)(src + i*8 + 4);
    ushortx8 o;
    o[0]=f2bf(a[0]); o[1]=f2bf(a[1]); o[2]=f2bf(a[2]); o[3]=f2bf(a[3]);
    o[4]=f2bf(b[0]); o[5]=f2bf(b[1]); o[6]=f2bf(b[2]); o[7]=f2bf(b[3]);
    *(ushortx8*)(dst + i*8) = o;
  }
}

__global__ void init_h_kernel(unsigned short* __restrict__ hb, unsigned int* __restrict__ ctr){
  int i = blockIdx.x*blockDim.x + threadIdx.x;
  hb[i] = 0;
  if (i < 8) ctr[i*32] = 0u;
}

// Persistent GRU, 256 WGs x 256 threads, 1 WG/CU, grp = bid&7 -> one XCD.
// Symmetric waves (R5 skeleton): each wave owns 32 rows x 16 cols, computes
// x-part (overlaps other WGs' step tail), polls, h-part (depth-4 pipelined
// sc0 loads), gates, publishes. Low-contention sync: per-WG LDS arrive counter
// -> 1 global add/WG/step; 1 global poller/WG -> LDS go broadcast.
__global__ __launch_bounds__(256) void gru_persist_kernel(
    const unsigned short* __restrict__ xb,
    const unsigned short* __restrict__ wihF, const unsigned short* __restrict__ whhF,
    const unsigned short* __restrict__ wihB, const unsigned short* __restrict__ whhB,
    const float* __restrict__ bihF, const float* __restrict__ bhhF,
    const float* __restrict__ bihB, const float* __restrict__ bhhB,
    const float* __restrict__ maskT,
    unsigned short* __restrict__ hb,
    float* __restrict__ out, unsigned int* __restrict__ ctr)
{
  const int bid   = blockIdx.x;
  const int grp   = bid & 7;       // XCD-local group (round-robin dispatch)
  const int strip = bid >> 3;      // 0..31
  const int dir   = grp >> 2;
  const int bslab = grp & 3;
  const int b0 = bslab * 128;
  const int n0 = strip * 16;
  unsigned int* myctr = ctr + grp*32;

  const unsigned short* wih = dir ? wihB : wihF;
  const unsigned short* whh = dir ? whhB : whhF;
  const float* bih = dir ? bihB : bihF;
  const float* bhh = dir ? bhhB : bhhF;

  const int tid  = threadIdx.x;
  const int lane = tid & 63;
  const int lr   = lane & 15;
  const int lkg  = lane >> 4;
  const int wv   = tid >> 6;        // 0..3
  const int wrow = wv * 32;

  __shared__ __align__(16) char smem[LDSTOT];
  unsigned int* arrive = (unsigned int*)(smem + LDSF);
  unsigned int* goflag = (unsigned int*)(smem + LDSF + 8);

  // ---- stage weights: x-panel + h-panel, [48 rows][1024B], row = gate*16+col,
  //      byte offset (kc*2) ^ ((row&15)<<4)  (R6-verified, conflict-free reads)
  for (int q = tid; q < 6144; q += 256) {
    const int p_  = q >= 3072;
    const int r_  = p_ ? (q - 3072) : q;
    const int row = r_ >> 6;                  // 0..47
    const int kc  = (r_ & 63) * 8;            // 0..504
    const unsigned short* src =
        (p_ ? whh : wih) + ((size_t)((row>>4)*HH + n0 + (row&15)))*512 + kc;
    *(ushortx8*)(smem + p_*LDSH + row*1024 + ((kc*2) ^ ((row&15)<<4))) =
        *(const ushortx8*)src;
  }
  if (tid == 0){ arrive[0] = 0u; goflag[0] = 0u; }
  __syncthreads();   // the only workgroup barrier

  const int jj = n0 + lr;
  const float br  = bih[jj]        + bhh[jj];
  const float bz  = bih[HH + jj]   + bhh[HH + jj];
  const float bnx = bih[2*HH + jj];
  const float bnh = bhh[2*HH + jj];

  float omax[2][4], hreg[2][4];
  #pragma unroll
  for (int mf=0; mf<2; ++mf)
    #pragma unroll
    for (int j=0; j<4; ++j){ omax[mf][j] = -FLT_MAX; hreg[mf][j] = 0.f; }

  const int swz = lr << 4;
  const char* wbx = smem + lr*1024;          // x-panel row for col jj
  const char* wbh = smem + LDSH + lr*1024;   // h-panel row for col jj

  for (int t = 0; t < TT; ++t) {
    const int tx = dir ? (TT-1-t) : t;
    const int bi = t & 1;
    const unsigned short* hbin = hb + (size_t)(dir*2 + bi)      * (BB*HH);
    unsigned short* hbout      = hb + (size_t)(dir*2 + (bi^1))  * (BB*HH);

    f32x4 ar[2], az[2], anx[2], anh[2];
    #pragma unroll
    for (int mf=0; mf<2; ++mf){ ar[mf]=0.f; az[mf]=0.f; anx[mf]=0.f; anh[mf]=0.f; }

    const unsigned short* xr0 = xb + ((size_t)(b0 + wrow + lr     )*TT + tx)*CC;
    const unsigned short* xr1 = xb + ((size_t)(b0 + wrow + 16 + lr)*TT + tx)*CC;

    // ---- x-part (K=0..511): no h dependency; absorbs inter-WG skew
    #pragma unroll
    for (int kk = 0; kk < 16; ++kk) {
      const int ko = kk*32 + lkg*8;
      bf16x8 a0 = *(const bf16x8*)(xr0 + ko);
      bf16x8 a1 = *(const bf16x8*)(xr1 + ko);
      const int kbx = (ko*2) ^ swz;
      bf16x8 brf = *(const bf16x8*)(wbx +         kbx);
      bf16x8 bzf = *(const bf16x8*)(wbx + 16384 + kbx);
      bf16x8 bnf = *(const bf16x8*)(wbx + 32768 + kbx);
      ar[0]  = __builtin_amdgcn_mfma_f32_16x16x32_bf16(a0, brf, ar[0],0,0,0);
      ar[1]  = __builtin_amdgcn_mfma_f32_16x16x32_bf16(a1, brf, ar[1],0,0,0);
      az[0]  = __builtin_amdgcn_mfma_f32_16x16x32_bf16(a0, bzf, az[0],0,0,0);
      az[1]  = __builtin_amdgcn_mfma_f32_16x16x32_bf16(a1, bzf, az[1],0,0,0);
      anx[0] = __builtin_amdgcn_mfma_f32_16x16x32_bf16(a0, bnf, anx[0],0,0,0);
      anx[1] = __builtin_amdgcn_mfma_f32_16x16x32_bf16(a1, bnf, anx[1],0,0,0);
    }

    // ---- mask loads (no h dependency)
    const float* mrow = maskT + tx*BB + b0 + wrow + lkg*4;
    const f32x4 mk0 = *(const f32x4*)(mrow);
    const f32x4 mk1 = *(const f32x4*)(mrow + 16);

    // ---- low-contention wait for step t's h: one global poller per WG,
    //      LDS go-flag broadcast to the other 3 waves
    if (t > 0) {
      if (wv == 0 && lane == 0) {
        const unsigned int tgt = 32u*(unsigned)t;
        unsigned int spin = 0;
        while (__hip_atomic_load(myctr, __ATOMIC_RELAXED, __HIP_MEMORY_SCOPE_AGENT) < tgt
               && ++spin < (1u<<24))
          __builtin_amdgcn_s_sleep(2);
        __hip_atomic_store(goflag, (unsigned)t, __ATOMIC_RELEASE, __HIP_MEMORY_SCOPE_WORKGROUP);
      }
      unsigned int spin = 0;
      while (__hip_atomic_load(goflag, __ATOMIC_ACQUIRE, __HIP_MEMORY_SCOPE_WORKGROUP) < (unsigned)t
             && ++spin < (1u<<24))
        __builtin_amdgcn_s_sleep(1);
    }

    WAITV(0);   // drain x/mask loads so h-pipeline vmcnt counting is exact

    // ---- h-part (K=0..511 of Whh): depth-4 pipelined sc0 loads
    const unsigned short* hr0 = hbin + (size_t)(b0 + wrow + lr     )*HH;
    const unsigned short* hr1 = hbin + (size_t)(b0 + wrow + 16 + lr)*HH;
    bf16x8 ph[4][2];
    #pragma unroll
    for (int q = 0; q < 4; ++q){
      ph[q][0] = load_sc0(hr0 + q*32 + lkg*8);
      ph[q][1] = load_sc0(hr1 + q*32 + lkg*8);
    }
    #pragma unroll
    for (int kk = 0; kk < 16; ++kk) {
      const int ko = kk*32 + lkg*8;
      const int kbx = (ko*2) ^ swz;
      bf16x8 brf = *(const bf16x8*)(wbh +         kbx);
      bf16x8 bzf = *(const bf16x8*)(wbh + 16384 + kbx);
      bf16x8 bnf = *(const bf16x8*)(wbh + 32768 + kbx);
      if (kk < 13)      { WAITV(6); }
      else if (kk == 13){ WAITV(4); }
      else if (kk == 14){ WAITV(2); }
      else              { WAITV(0); }
      bf16x8 c0 = ph[kk&3][0];
      bf16x8 c1 = ph[kk&3][1];
      ar[0]  = __builtin_amdgcn_mfma_f32_16x16x32_bf16(c0, brf, ar[0],0,0,0);
      ar[1]  = __builtin_amdgcn_mfma_f32_16x16x32_bf16(c1, brf, ar[1],0,0,0);
      az[0]  = __builtin_amdgcn_mfma_f32_16x16x32_bf16(c0, bzf, az[0],0,0,0);
      az[1]  = __builtin_amdgcn_mfma_f32_16x16x32_bf16(c1, bzf, az[1],0,0,0);
      anh[0] = __builtin_amdgcn_mfma_f32_16x16x32_bf16(c0, bnf, anh[0],0,0,0);
      anh[1] = __builtin_amdgcn_mfma_f32_16x16x32_bf16(c1, bnf, anh[1],0,0,0);
      if (kk < 12) {
        ph[kk&3][0] = load_sc0(hr0 + (kk+4)*32 + lkg*8);
        ph[kk&3][1] = load_sc0(hr1 + (kk+4)*32 + lkg*8);
      }
    }

    // ---- epilogue: gates, register h carry, register max-pool
    #pragma unroll
    for (int mf=0; mf<2; ++mf){
      const f32x4 mk = mf ? mk1 : mk0;
      #pragma unroll
      for (int j=0; j<4; ++j){
        const int b = b0 + wrow + mf*16 + lkg*4 + j;
        const float rg = fast_sigmoid(ar[mf][j] + br);
        const float zg = fast_sigmoid(az[mf][j] + bz);
        const float ng = fast_tanh(anx[mf][j] + bnx + rg*(anh[mf][j] + bnh));
        const float hn = (1.f - zg)*ng + zg*hreg[mf][j];
        hreg[mf][j] = hn;
        hbout[(size_t)b*HH + jj] = f2bf(hn);
        const float cand = (mk[j] != 0.f) ? hn : -FLT_MAX;
        omax[mf][j] = fmaxf(omax[mf][j], cand);
      }
    }

    // ---- publish: per-wave drain -> LDS arrive; wave0 waits arrive==4*(t+1),
    //      does the single global add for this WG
    if (t < TT-1) {
      WAITV(0);   // own h stores drained to L2
      if (lane == 0)
        __hip_atomic_fetch_add(arrive, 1u, __ATOMIC_RELEASE, __HIP_MEMORY_SCOPE_WORKGROUP);
      if (wv == 0 && lane == 0) {
        const unsigned int tgt = 4u*(unsigned)(t+1);
        unsigned int spin = 0;
        while (__hip_atomic_load(arrive, __ATOMIC_ACQUIRE, __HIP_MEMORY_SCOPE_WORKGROUP) < tgt
               && ++spin < (1u<<24))
          __builtin_amdgcn_s_sleep(1);
        __hip_atomic_fetch_add(myctr, 1u, __ATOMIC_RELAXED, __HIP_MEMORY_SCOPE_AGENT);
      }
    }
  }

  // ---- final masked-max write: out[b][dir*H + jj]
  #pragma unroll
  for (int mf=0; mf<2; ++mf)
    #pragma unroll
    for (int j=0; j<4; ++j){
      const int b = b0 + wrow + mf*16 + lkg*4 + j;
      out[(size_t)b*(2*HH) + dir*HH + jj] = omax[mf][j];
    }
}

extern "C" void kernel_launch(void* const* d_in, const int* in_sizes, int n_in,
                              void* d_out, int out_size, void* d_ws, size_t ws_size,
                              hipStream_t stream) {
  const float* x    = (const float*)d_in[0];
  const float* WihF = (const float*)d_in[1];
  const float* WhhF = (const float*)d_in[2];
  const float* bihF = (const float*)d_in[3];
  const float* bhhF = (const float*)d_in[4];
  const float* WihB = (const float*)d_in[5];
  const float* WhhB = (const float*)d_in[6];
  const float* bihB = (const float*)d_in[7];
  const float* bhhB = (const float*)d_in[8];
  float* out = (float*)d_out;

  char* ws = (char*)d_ws;
  unsigned short* xb    = (unsigned short*)(ws);              // B*T*C bf16
  unsigned short* wb    = (unsigned short*)(ws + 20971520);
  unsigned short* wihFb = wb;
  unsigned short* whhFb = wb + 786432;
  unsigned short* wihBb = wb + 2*786432;
  unsigned short* whhBb = wb + 3*786432;
  float* maskT = (float*)(ws + 27262976);                     // [T][B]
  unsigned short* hb = (unsigned short*)(ws + 27344896);      // [2dir][2buf][B][H] bf16
  unsigned int* ctr  = (unsigned int*)(ws + 29442048);        // 8 counters, 128B stride

  prep_x_kernel<<<BB*TT/4, 256, 0, stream>>>(x, xb, maskT);
  cvt_kernel<<<384, 256, 0, stream>>>(WihF, wihFb, 98304);
  cvt_kernel<<<384, 256, 0, stream>>>(WhhF, whhFb, 98304);
  cvt_kernel<<<384, 256, 0, stream>>>(WihB, wihBb, 98304);
  cvt_kernel<<<384, 256, 0, stream>>>(WhhB, whhBb, 98304);
  init_h_kernel<<<4096, 256, 0, stream>>>(hb, ctr);

  gru_persist_kernel<<<256, 256, 0, stream>>>(xb, wihFb, whhFb, wihBb, whhBb,
                                              bihF, bhhF, bihB, bhhB,
                                              maskT, hb, out, ctr);
}

// Round 8
// 335.499 us; speedup vs baseline: 2.7355x; 1.1056x over previous
//
#include <hip/hip_runtime.h>
#include <hip/hip_bf16.h>
#include <float.h>

#define BB 512
#define TT 40
#define CC 512
#define HH 512

typedef short bf16x8 __attribute__((ext_vector_type(8)));
typedef float f32x4 __attribute__((ext_vector_type(4)));
typedef unsigned short ushortx8 __attribute__((ext_vector_type(8)));

// LDS map (bytes): x-panel [48][1024B] | h-panel [48][1024B] | arrive counter
#define LDSH 49152
#define LDSF 98304
#define LDSTOT 98320

__device__ __forceinline__ unsigned short f2bf(float f){
  union { float f; unsigned int i; } v; v.f = f;
  unsigned int r = v.i + 0x7fffu + ((v.i >> 16) & 1u);
  return (unsigned short)(r >> 16);
}

__device__ __forceinline__ bf16x8 load_sc0(const unsigned short* p){
  bf16x8 r;
  asm volatile("global_load_dwordx4 %0, %1, off sc0" : "=v"(r) : "v"(p));
  return r;
}
#define WAITV(N) do { asm volatile("s_waitcnt vmcnt(" #N ")" ::: "memory"); \
                      __builtin_amdgcn_sched_barrier(0); } while(0)

__device__ __forceinline__ float fast_sigmoid(float x){
  return __builtin_amdgcn_rcpf(1.f + __expf(-x));
}
__device__ __forceinline__ float fast_tanh(float x){
  return 1.f - 2.f*__builtin_amdgcn_rcpf(__expf(2.f*x) + 1.f);
}

// one wave per (b,t): convert 512 floats -> bf16, compute nonzero mask (transposed [T][B])
__global__ void prep_x_kernel(const float* __restrict__ x, unsigned short* __restrict__ xb,
                              float* __restrict__ maskT){
  int w = blockIdx.x*4 + (threadIdx.x>>6);
  int lane = threadIdx.x & 63;
  const float* src = x + (size_t)w*CC + lane*8;
  f32x4 a = *(const f32x4*)(src);
  f32x4 b = *(const f32x4*)(src+4);
  ushortx8 o;
  o[0]=f2bf(a[0]); o[1]=f2bf(a[1]); o[2]=f2bf(a[2]); o[3]=f2bf(a[3]);
  o[4]=f2bf(b[0]); o[5]=f2bf(b[1]); o[6]=f2bf(b[2]); o[7]=f2bf(b[3]);
  *(ushortx8*)(xb + (size_t)w*CC + lane*8) = o;
  bool nz = (a[0]!=0.f)||(a[1]!=0.f)||(a[2]!=0.f)||(a[3]!=0.f)||
            (b[0]!=0.f)||(b[1]!=0.f)||(b[2]!=0.f)||(b[3]!=0.f);
  unsigned long long bal = __ballot(nz);
  if (lane==0){
    int b_ = w / TT, t_ = w % TT;
    maskT[t_*BB + b_] = bal ? 1.0f : 0.0f;
  }
}

// vectorized f32 -> bf16 weight convert (8 elems/thread)
__global__ void cvt_kernel(const float* __restrict__ src, unsigned short* __restrict__ dst, int n8){
  int i = blockIdx.x*blockDim.x + threadIdx.x;
  if (i < n8){
    f32x4 a = *(const f32x4*)(src + i*8);
    f32x4 b = *(const f32x4*)(src + i*8 + 4);
    ushortx8 o;
    o[0]=f2bf(a[0]); o[1]=f2bf(a[1]); o[2]=f2bf(a[2]); o[3]=f2bf(a[3]);
    o[4]=f2bf(b[0]); o[5]=f2bf(b[1]); o[6]=f2bf(b[2]); o[7]=f2bf(b[3]);
    *(ushortx8*)(dst + i*8) = o;
  }
}

__global__ void init_h_kernel(unsigned short* __restrict__ hb, unsigned int* __restrict__ ctr){
  int i = blockIdx.x*blockDim.x + threadIdx.x;
  hb[i] = 0;
  if (i < 8) ctr[i*32] = 0u;
}

// Persistent GRU, 256 WGs x 512 threads (8 waves), 1 WG/CU, 2 waves/SIMD.
// Symmetric re-tile of R5/R7: each wave owns 16 rows x 16 cols and runs the
// full x-part -> poll -> h-part -> epilogue pipeline independently; the two
// waves per SIMD give TLP so one wave's stalls hide under the other's MFMAs.
// Sync: all waves direct-poll the group counter (1 hop); publish via LDS
// arrive counter -> single global add per WG per step (32 adders/group).
__global__ __launch_bounds__(512, 2) void gru_persist_kernel(
    const unsigned short* __restrict__ xb,
    const unsigned short* __restrict__ wihF, const unsigned short* __restrict__ whhF,
    const unsigned short* __restrict__ wihB, const unsigned short* __restrict__ whhB,
    const float* __restrict__ bihF, const float* __restrict__ bhhF,
    const float* __restrict__ bihB, const float* __restrict__ bhhB,
    const float* __restrict__ maskT,
    unsigned short* __restrict__ hb,
    float* __restrict__ out, unsigned int* __restrict__ ctr)
{
  const int bid   = blockIdx.x;
  const int grp   = bid & 7;       // XCD-local group (round-robin dispatch)
  const int strip = bid >> 3;      // 0..31
  const int dir   = grp >> 2;
  const int bslab = grp & 3;
  const int b0 = bslab * 128;
  const int n0 = strip * 16;
  unsigned int* myctr = ctr + grp*32;

  const unsigned short* wih = dir ? wihB : wihF;
  const unsigned short* whh = dir ? whhB : whhF;
  const float* bih = dir ? bihB : bihF;
  const float* bhh = dir ? bhhB : bhhF;

  const int tid  = threadIdx.x;
  const int lane = tid & 63;
  const int lr   = lane & 15;
  const int lkg  = lane >> 4;
  const int wv   = tid >> 6;        // 0..7
  const int wrow = wv * 16;         // wave's 16-row slice

  __shared__ __align__(16) char smem[LDSTOT];
  unsigned int* arrive = (unsigned int*)(smem + LDSF);

  // ---- stage weights: x-panel + h-panel, [48 rows][1024B], row = gate*16+col,
  //      byte offset (kc*2) ^ ((row&15)<<4)  (conflict-free reads, R7-verified)
  for (int q = tid; q < 6144; q += 512) {
    const int p_  = q >= 3072;
    const int r_  = p_ ? (q - 3072) : q;
    const int row = r_ >> 6;                  // 0..47
    const int kc  = (r_ & 63) * 8;            // 0..504
    const unsigned short* src =
        (p_ ? whh : wih) + ((size_t)((row>>4)*HH + n0 + (row&15)))*512 + kc;
    *(ushortx8*)(smem + p_*LDSH + row*1024 + ((kc*2) ^ ((row&15)<<4))) =
        *(const ushortx8*)src;
  }
  if (tid == 0) arrive[0] = 0u;
  __syncthreads();   // the only workgroup barrier

  const int jj = n0 + lr;
  const float br  = bih[jj]        + bhh[jj];
  const float bz  = bih[HH + jj]   + bhh[HH + jj];
  const float bnx = bih[2*HH + jj];
  const float bnh = bhh[2*HH + jj];

  float omax[4], hreg[4];
  #pragma unroll
  for (int j=0; j<4; ++j){ omax[j] = -FLT_MAX; hreg[j] = 0.f; }

  const int swz = lr << 4;
  const char* wbx = smem + lr*1024;          // x-panel row for col jj
  const char* wbh = smem + LDSH + lr*1024;   // h-panel row for col jj

  for (int t = 0; t < TT; ++t) {
    const int tx = dir ? (TT-1-t) : t;
    const int bi = t & 1;
    const unsigned short* hbin = hb + (size_t)(dir*2 + bi)      * (BB*HH);
    unsigned short* hbout      = hb + (size_t)(dir*2 + (bi^1))  * (BB*HH);

    f32x4 ar = 0.f, az = 0.f, anx = 0.f, anh = 0.f;

    const unsigned short* xr0 = xb + ((size_t)(b0 + wrow + lr)*TT + tx)*CC;

    // ---- x-part (K=0..511): no h dependency; absorbs inter-WG skew
    #pragma unroll
    for (int kk = 0; kk < 16; ++kk) {
      const int ko = kk*32 + lkg*8;
      bf16x8 a0 = *(const bf16x8*)(xr0 + ko);
      const int kbx = (ko*2) ^ swz;
      bf16x8 brf = *(const bf16x8*)(wbx +         kbx);
      bf16x8 bzf = *(const bf16x8*)(wbx + 16384 + kbx);
      bf16x8 bnf = *(const bf16x8*)(wbx + 32768 + kbx);
      ar  = __builtin_amdgcn_mfma_f32_16x16x32_bf16(a0, brf, ar,0,0,0);
      az  = __builtin_amdgcn_mfma_f32_16x16x32_bf16(a0, bzf, az,0,0,0);
      anx = __builtin_amdgcn_mfma_f32_16x16x32_bf16(a0, bnf, anx,0,0,0);
    }

    // ---- mask load (no h dependency)
    const f32x4 mk = *(const f32x4*)(maskT + tx*BB + b0 + wrow + lkg*4);

    // ---- direct wait for step t's h (wave-uniform poll, one hop)
    if (t > 0) {
      const unsigned int tgt = 32u*(unsigned)t;
      unsigned int spin = 0;
      while (__hip_atomic_load(myctr, __ATOMIC_RELAXED, __HIP_MEMORY_SCOPE_AGENT) < tgt
             && ++spin < (1u<<24))
        __builtin_amdgcn_s_sleep(1);
    }

    WAITV(0);   // drain x/mask loads so h-pipeline vmcnt counting is exact

    // ---- h-part (K=0..511 of Whh): depth-4 pipelined sc0 loads, 1 load/kk
    const unsigned short* hr0 = hbin + (size_t)(b0 + wrow + lr)*HH;
    bf16x8 ph[4];
    #pragma unroll
    for (int q = 0; q < 4; ++q)
      ph[q] = load_sc0(hr0 + q*32 + lkg*8);
    #pragma unroll
    for (int kk = 0; kk < 16; ++kk) {
      const int ko = kk*32 + lkg*8;
      const int kbx = (ko*2) ^ swz;
      bf16x8 brf = *(const bf16x8*)(wbh +         kbx);
      bf16x8 bzf = *(const bf16x8*)(wbh + 16384 + kbx);
      bf16x8 bnf = *(const bf16x8*)(wbh + 32768 + kbx);
      if (kk < 13)      { WAITV(3); }
      else if (kk == 13){ WAITV(2); }
      else if (kk == 14){ WAITV(1); }
      else              { WAITV(0); }
      bf16x8 c0 = ph[kk&3];
      ar  = __builtin_amdgcn_mfma_f32_16x16x32_bf16(c0, brf, ar,0,0,0);
      az  = __builtin_amdgcn_mfma_f32_16x16x32_bf16(c0, bzf, az,0,0,0);
      anh = __builtin_amdgcn_mfma_f32_16x16x32_bf16(c0, bnf, anh,0,0,0);
      if (kk < 12)
        ph[kk&3] = load_sc0(hr0 + (kk+4)*32 + lkg*8);
    }

    // ---- epilogue: gates, register h carry, register max-pool
    #pragma unroll
    for (int j=0; j<4; ++j){
      const int b = b0 + wrow + lkg*4 + j;
      const float rg = fast_sigmoid(ar[j] + br);
      const float zg = fast_sigmoid(az[j] + bz);
      const float ng = fast_tanh(anx[j] + bnx + rg*(anh[j] + bnh));
      const float hn = (1.f - zg)*ng + zg*hreg[j];
      hreg[j] = hn;
      hbout[(size_t)b*HH + jj] = f2bf(hn);
      const float cand = (mk[j] != 0.f) ? hn : -FLT_MAX;
      omax[j] = fmaxf(omax[j], cand);
    }

    // ---- publish: per-wave drain -> LDS arrive; wave0 waits arrive==8*(t+1),
    //      does the single global add for this WG
    if (t < TT-1) {
      WAITV(0);   // own h stores drained to L2
      if (lane == 0)
        __hip_atomic_fetch_add(arrive, 1u, __ATOMIC_RELEASE, __HIP_MEMORY_SCOPE_WORKGROUP);
      if (wv == 0 && lane == 0) {
        const unsigned int tgt = 8u*(unsigned)(t+1);
        unsigned int spin = 0;
        while (__hip_atomic_load(arrive, __ATOMIC_ACQUIRE, __HIP_MEMORY_SCOPE_WORKGROUP) < tgt
               && ++spin < (1u<<24))
          __builtin_amdgcn_s_sleep(1);
        __hip_atomic_fetch_add(myctr, 1u, __ATOMIC_RELAXED, __HIP_MEMORY_SCOPE_AGENT);
      }
    }
  }

  // ---- final masked-max write: out[b][dir*H + jj]
  #pragma unroll
  for (int j=0; j<4; ++j){
    const int b = b0 + wrow + lkg*4 + j;
    out[(size_t)b*(2*HH) + dir*HH + jj] = omax[j];
  }
}

extern "C" void kernel_launch(void* const* d_in, const int* in_sizes, int n_in,
                              void* d_out, int out_size, void* d_ws, size_t ws_size,
                              hipStream_t stream) {
  const float* x    = (const float*)d_in[0];
  const float* WihF = (const float*)d_in[1];
  const float* WhhF = (const float*)d_in[2];
  const float* bihF = (const float*)d_in[3];
  const float* bhhF = (const float*)d_in[4];
  const float* WihB = (const float*)d_in[5];
  const float* WhhB = (const float*)d_in[6];
  const float* bihB = (const float*)d_in[7];
  const float* bhhB = (const float*)d_in[8];
  float* out = (float*)d_out;

  char* ws = (char*)d_ws;
  unsigned short* xb    = (unsigned short*)(ws);              // B*T*C bf16
  unsigned short* wb    = (unsigned short*)(ws + 20971520);
  unsigned short* wihFb = wb;
  unsigned short* whhFb = wb + 786432;
  unsigned short* wihBb = wb + 2*786432;
  unsigned short* whhBb = wb + 3*786432;
  float* maskT = (float*)(ws + 27262976);                     // [T][B]
  unsigned short* hb = (unsigned short*)(ws + 27344896);      // [2dir][2buf][B][H] bf16
  unsigned int* ctr  = (unsigned int*)(ws + 29442048);        // 8 counters, 128B stride

  prep_x_kernel<<<BB*TT/4, 256, 0, stream>>>(x, xb, maskT);
  cvt_kernel<<<384, 256, 0, stream>>>(WihF, wihFb, 98304);
  cvt_kernel<<<384, 256, 0, stream>>>(WhhF, whhFb, 98304);
  cvt_kernel<<<384, 256, 0, stream>>>(WihB, wihBb, 98304);
  cvt_kernel<<<384, 256, 0, stream>>>(WhhB, whhBb, 98304);
  init_h_kernel<<<4096, 256, 0, stream>>>(hb, ctr);

  gru_persist_kernel<<<256, 512, 0, stream>>>(xb, wihFb, whhFb, wihBb, whhBb,
                                              bihF, bhhF, bihB, bhhB,
                                              maskT, hb, out, ctr);
}